// Round 7
// baseline (250.296 us; speedup 1.0000x reference)
//
#include <hip/hip_runtime.h>
#include <hip/hip_bf16.h>

#define DIM 512
#define HEADS 8
#define DHEAD 64
#define INNER 512
#define NSEQ 1024
#define BATCH 8
#define MROWS (BATCH*NSEQ)
#define QK_SCALE 0.125f
#define LOG2E 1.44269504f

typedef __attribute__((ext_vector_type(4))) float f32x4;
typedef __attribute__((ext_vector_type(8))) short short8;
typedef unsigned short ushort_t;

__device__ inline ushort_t f2bf(float f) {
    __hip_bfloat16 h = __float2bfloat16(f);
    return *reinterpret_cast<ushort_t*>(&h);
}
__device__ inline float bf2f(ushort_t u) {
    union { unsigned int i; float f; } c; c.i = ((unsigned int)u) << 16; return c.f;
}
__device__ inline float fast_exp2(float x) {
    float r; asm("v_exp_f32 %0, %1" : "=v"(r) : "v"(x)); return r;
}

// ---------------- fused prep: LN + weight transposes + bias cvt(*LOG2E) ----------------
// region dispatch on blockIdx.x:
//   [0,2048)        : layernorm, 4 rows/block
//   [2048,2240)     : transpose w_qkv (24 x 8 tiles of 64x64)
//   [2240,2304)     : transpose w_out (8 x 8 tiles)
//   [2304,10496)    : bias f32 -> bf16 * LOG2E
__device__ inline void tc_tile(const float* __restrict__ w, ushort_t* __restrict__ wt,
        int ncols, int n0, int k0, int t, ushort_t (*T)[72]) {
    int kr = t >> 2;
    int nc = (t & 3) * 16;
    const float4* src = (const float4*)(w + (size_t)(k0 + kr) * ncols + n0 + nc);
    float4 f0 = src[0], f1 = src[1], f2 = src[2], f3 = src[3];
    ushort_t tmp[16];
    tmp[0]=f2bf(f0.x); tmp[1]=f2bf(f0.y); tmp[2]=f2bf(f0.z); tmp[3]=f2bf(f0.w);
    tmp[4]=f2bf(f1.x); tmp[5]=f2bf(f1.y); tmp[6]=f2bf(f1.z); tmp[7]=f2bf(f1.w);
    tmp[8]=f2bf(f2.x); tmp[9]=f2bf(f2.y); tmp[10]=f2bf(f2.z); tmp[11]=f2bf(f2.w);
    tmp[12]=f2bf(f3.x); tmp[13]=f2bf(f3.y); tmp[14]=f2bf(f3.z); tmp[15]=f2bf(f3.w);
    *(uint4*)&T[kr][nc]     = *(uint4*)&tmp[0];
    *(uint4*)&T[kr][nc + 8] = *(uint4*)&tmp[8];
    __syncthreads();
    int nr = t >> 2;
    int kc = (t & 3) * 16;
    ushort_t o[16];
    for (int j = 0; j < 16; j++) o[j] = T[kc + j][nr];
    ushort_t* dst = wt + (size_t)(n0 + nr) * 512 + k0 + kc;
    *(uint4*)(dst)     = *(uint4*)&o[0];
    *(uint4*)(dst + 8) = *(uint4*)&o[8];
}

__global__ __launch_bounds__(256) void prep_kernel(
        const float* __restrict__ x, const float* __restrict__ gamma,
        const float* __restrict__ beta, ushort_t* __restrict__ xn,
        const float* __restrict__ w_qkv, ushort_t* __restrict__ wqkvT,
        const float* __restrict__ w_out, ushort_t* __restrict__ woutT,
        const float* __restrict__ bias, ushort_t* __restrict__ biasb) {
    __shared__ ushort_t T[64][72];
    int bid = blockIdx.x;
    int t = threadIdx.x;
    if (bid < 2048) {
        int row = bid * 4 + (t >> 6);
        int lane = t & 63;
        const float4* xr = (const float4*)(x + (size_t)row * DIM);
        float4 a0 = xr[lane];
        float4 a1 = xr[lane + 64];
        float s  = a0.x + a0.y + a0.z + a0.w + a1.x + a1.y + a1.z + a1.w;
        float ss = a0.x*a0.x + a0.y*a0.y + a0.z*a0.z + a0.w*a0.w
                 + a1.x*a1.x + a1.y*a1.y + a1.z*a1.z + a1.w*a1.w;
        for (int off = 1; off < 64; off <<= 1) {
            s  += __shfl_xor(s, off);
            ss += __shfl_xor(ss, off);
        }
        float mean = s * (1.0f / DIM);
        float var  = ss * (1.0f / DIM) - mean * mean;
        float inv  = rsqrtf(var + 1e-5f);
        const float4* g4 = (const float4*)gamma;
        const float4* b4 = (const float4*)beta;
        float4 g0 = g4[lane], g1 = g4[lane + 64];
        float4 be0 = b4[lane], be1 = b4[lane + 64];
        ushort4 o0, o1;
        o0.x = f2bf((a0.x - mean) * inv * g0.x + be0.x);
        o0.y = f2bf((a0.y - mean) * inv * g0.y + be0.y);
        o0.z = f2bf((a0.z - mean) * inv * g0.z + be0.z);
        o0.w = f2bf((a0.w - mean) * inv * g0.w + be0.w);
        o1.x = f2bf((a1.x - mean) * inv * g1.x + be1.x);
        o1.y = f2bf((a1.y - mean) * inv * g1.y + be1.y);
        o1.z = f2bf((a1.z - mean) * inv * g1.z + be1.z);
        o1.w = f2bf((a1.w - mean) * inv * g1.w + be1.w);
        ushort4* outr = (ushort4*)(xn + (size_t)row * DIM);
        outr[lane] = o0;
        outr[lane + 64] = o1;
    } else if (bid < 2240) {
        int rel = bid - 2048;
        tc_tile(w_qkv, wqkvT, 1536, (rel % 24) * 64, (rel / 24) * 64, t, T);
    } else if (bid < 2304) {
        int rel = bid - 2240;
        tc_tile(w_out, woutT, 512, (rel % 8) * 64, (rel / 8) * 64, t, T);
    } else {
        int rel = bid - 2304;
        int i = rel * 256 + t;
        float4 v = ((const float4*)bias)[i];
        ushort4 o;
        o.x = f2bf(v.x * LOG2E); o.y = f2bf(v.y * LOG2E);
        o.z = f2bf(v.z * LOG2E); o.w = f2bf(v.w * LOG2E);
        ((ushort4*)biasb)[i] = o;
    }
}

// ---------------- GEMM: A[M][512] bf16 x Bt[N][512] bf16, BK=64, 2-phase prefetch ----------------
// tile 128 x BN, 4 waves (2x2). Swapped MFMA -> lane owns (row=l15, 4 consecutive cols).
// EPI==0: QKV epilogue, q scaled by QK_SCALE*LOG2E, V written transposed to vt[b,h,d,seq].
// EPI==1: out = acc + b_out (f32).
template<int EPI, int BN>
__global__ __launch_bounds__(256) void gemm_kernel(
        const ushort_t* __restrict__ A, const ushort_t* __restrict__ Bt,
        ushort_t* __restrict__ qb, ushort_t* __restrict__ kb, ushort_t* __restrict__ vtb,
        float* __restrict__ outp, const float* __restrict__ bvec) {
    constexpr int BNF = BN / 32;          // n-frags per wave
    __shared__ ushort_t Als[128][72];
    __shared__ ushort_t Bls[BN][72];
    int t = threadIdx.x;
    int bm = blockIdx.y, bn = blockIdx.x;
    int lane = t & 63, w = t >> 6, wm = w >> 1, wn = w & 1;
    int l15 = lane & 15, l4 = lane >> 4;
    f32x4 acc[4][BNF] = {};

    int ra = t >> 1, ca = (t & 1) * 32;   // A staging: 4 x uint4 per thread
    int rb, cb_;
    if constexpr (BN == 128) { rb = t >> 1; cb_ = (t & 1) * 32; }
    else                     { rb = t >> 2; cb_ = (t & 3) * 16; }

    uint4 ar[4], br[BN == 128 ? 4 : 2];
    {
        const ushort_t* ap = A  + (size_t)(bm*128 + ra) * DIM + ca;
        for (int i = 0; i < 4; i++) ar[i] = *(const uint4*)(ap + i*8);
        const ushort_t* bp = Bt + (size_t)(bn*BN + rb) * DIM + cb_;
        for (int i = 0; i < (BN == 128 ? 4 : 2); i++) br[i] = *(const uint4*)(bp + i*8);
    }

    for (int kt = 0; kt < DIM / 64; ++kt) {
        __syncthreads();
        for (int i = 0; i < 4; i++) *(uint4*)&Als[ra][ca + i*8] = ar[i];
        for (int i = 0; i < (BN == 128 ? 4 : 2); i++) *(uint4*)&Bls[rb][cb_ + i*8] = br[i];
        __syncthreads();
        if (kt + 1 < DIM / 64) {
            const ushort_t* ap = A  + (size_t)(bm*128 + ra) * DIM + (kt+1)*64 + ca;
            for (int i = 0; i < 4; i++) ar[i] = *(const uint4*)(ap + i*8);
            const ushort_t* bp = Bt + (size_t)(bn*BN + rb) * DIM + (kt+1)*64 + cb_;
            for (int i = 0; i < (BN == 128 ? 4 : 2); i++) br[i] = *(const uint4*)(bp + i*8);
        }
        for (int ks = 0; ks < 2; ks++) {
            short8 af[4], bfr[BNF];
            for (int mi = 0; mi < 4; mi++)   af[mi]  = *(const short8*)&Als[wm*64 + mi*16 + l15][ks*32 + l4*8];
            for (int ni = 0; ni < BNF; ni++) bfr[ni] = *(const short8*)&Bls[wn*(BN/2) + ni*16 + l15][ks*32 + l4*8];
            __builtin_amdgcn_s_setprio(1);
            for (int mi = 0; mi < 4; mi++)
                for (int ni = 0; ni < BNF; ni++)
                    acc[mi][ni] = __builtin_amdgcn_mfma_f32_16x16x32_bf16(bfr[ni], af[mi], acc[mi][ni], 0, 0, 0);
            __builtin_amdgcn_s_setprio(0);
        }
    }

    for (int mi = 0; mi < 4; mi++) {
        int r = bm*128 + wm*64 + mi*16 + l15;
        for (int ni = 0; ni < BNF; ni++) {
            int c = bn*BN + wn*(BN/2) + ni*16 + l4*4;
            f32x4 v = acc[mi][ni];
            if (EPI == 0) {
                int part = c >> 9, cw = c & 511;
                int h = cw >> 6, d = cw & 63;
                int b = r >> 10, i = r & 1023;
                size_t bh = (size_t)(b*HEADS + h);
                if (part == 0) {
                    ushort4 o;
                    o.x = f2bf(v[0] * (QK_SCALE*LOG2E)); o.y = f2bf(v[1] * (QK_SCALE*LOG2E));
                    o.z = f2bf(v[2] * (QK_SCALE*LOG2E)); o.w = f2bf(v[3] * (QK_SCALE*LOG2E));
                    *(ushort4*)(qb + (bh * NSEQ + i) * DHEAD + d) = o;
                } else if (part == 1) {
                    ushort4 o;
                    o.x = f2bf(v[0]); o.y = f2bf(v[1]); o.z = f2bf(v[2]); o.w = f2bf(v[3]);
                    *(ushort4*)(kb + (bh * NSEQ + i) * DHEAD + d) = o;
                } else {
                    // V transposed: vt[b,h,d,seq]
                    for (int j = 0; j < 4; j++)
                        vtb[(bh * DHEAD + d + j) * NSEQ + i] = f2bf(v[j]);
                }
            } else {
                float4 bv = *(const float4*)(bvec + c);
                float4 o2;
                o2.x = v[0] + bv.x; o2.y = v[1] + bv.y;
                o2.z = v[2] + bv.z; o2.w = v[3] + bv.w;
                *(float4*)(outp + (size_t)r * DIM + c) = o2;
            }
        }
    }
}

// ---------------- flash attention, swapped-operand (S^T), exp2 domain ----------------
// T14 prefetch for K/V AND bias; T13 defer-max; T5 setprio.
__global__ __launch_bounds__(256) void attn_kernel(
        const ushort_t* __restrict__ q, const ushort_t* __restrict__ k,
        const ushort_t* __restrict__ vt, const ushort_t* __restrict__ biasb,
        ushort_t* __restrict__ attno) {
    __shared__ ushort_t Kls[64][72];
    __shared__ ushort_t Vtls[64][72];
    __shared__ ushort_t Pls[4][16][72];
    int t = threadIdx.x, lane = t & 63, w = t >> 6;
    int l15 = lane & 15, l4 = lane >> 4;
    int b = blockIdx.z, h = blockIdx.y, q0 = blockIdx.x * 64;
    size_t bh = (size_t)(b * HEADS + h);
    const ushort_t* qp = q  + (bh * NSEQ + q0 + w*16) * DHEAD;
    const ushort_t* kp = k  + bh * NSEQ * DHEAD;
    const ushort_t* vp = vt + bh * DHEAD * NSEQ;
    int qrow = q0 + w*16 + l15;
    const ushort_t* bp = biasb + ((size_t)h * NSEQ + qrow) * NSEQ;

    short8 bq[2];
    bq[0] = *(const short8*)(qp + l15*DHEAD + l4*8);
    bq[1] = *(const short8*)(qp + l15*DHEAD + l4*8 + 32);

    f32x4 o[4] = {};
    float mrun = -INFINITY, lrun = 0.f;

    int srow = t >> 2, sc = (t & 3) * 16;

    // prologue: prefetch tile 0 (K, V, bias) into regs
    uint4 kreg0, kreg1, vreg0, vreg1;
    ushort4 cb[4], nb[4];
    {
        const ushort_t* ks0 = kp + (size_t)srow * DHEAD + sc;
        const ushort_t* vs0 = vp + (size_t)srow * NSEQ + sc;
        kreg0 = *(const uint4*)(ks0);
        kreg1 = *(const uint4*)(ks0 + 8);
        vreg0 = *(const uint4*)(vs0);
        vreg1 = *(const uint4*)(vs0 + 8);
        for (int ni = 0; ni < 4; ni++)
            cb[ni] = *(const ushort4*)(bp + ni*16 + l4*4);
    }

    for (int kt = 0; kt < NSEQ / 64; ++kt) {
        __syncthreads();
        *(uint4*)&Kls[srow][sc]      = kreg0;
        *(uint4*)&Kls[srow][sc + 8]  = kreg1;
        *(uint4*)&Vtls[srow][sc]     = vreg0;
        *(uint4*)&Vtls[srow][sc + 8] = vreg1;
        __syncthreads();

        // prefetch next K/V tile (latency hides under compute below)
        if (kt + 1 < NSEQ / 64) {
            const ushort_t* ksn = kp + (size_t)((kt+1)*64 + srow) * DHEAD + sc;
            const ushort_t* vsn = vp + (size_t)srow * NSEQ + (kt+1)*64 + sc;
            kreg0 = *(const uint4*)(ksn);
            kreg1 = *(const uint4*)(ksn + 8);
            vreg0 = *(const uint4*)(vsn);
            vreg1 = *(const uint4*)(vsn + 8);
        }

        // S^T = K x Q^T (log2-domain scores: q pre-scaled by SCALE*log2e)
        f32x4 s[4];
        __builtin_amdgcn_s_setprio(1);
        for (int ni = 0; ni < 4; ni++) {
            f32x4 z = {};
            short8 ak0 = *(const short8*)&Kls[ni*16 + l15][l4*8];
            short8 ak1 = *(const short8*)&Kls[ni*16 + l15][l4*8 + 32];
            z = __builtin_amdgcn_mfma_f32_16x16x32_bf16(ak0, bq[0], z, 0, 0, 0);
            z = __builtin_amdgcn_mfma_f32_16x16x32_bf16(ak1, bq[1], z, 0, 0, 0);
            s[ni] = z;
        }
        __builtin_amdgcn_s_setprio(0);

        // bias add + softmax (defer-max, log2 units)
        float p[16];
        float mj = -INFINITY;
        for (int ni = 0; ni < 4; ni++) {
            ushort4 b4 = cb[ni];
            float v0 = s[ni][0] + bf2f(b4.x);
            float v1 = s[ni][1] + bf2f(b4.y);
            float v2 = s[ni][2] + bf2f(b4.z);
            float v3 = s[ni][3] + bf2f(b4.w);
            p[ni*4+0] = v0; p[ni*4+1] = v1; p[ni*4+2] = v2; p[ni*4+3] = v3;
            mj = fmaxf(mj, fmaxf(fmaxf(v0, v1), fmaxf(v2, v3)));
        }
        mj = fmaxf(mj, __shfl_xor(mj, 16));
        mj = fmaxf(mj, __shfl_xor(mj, 32));
        // prefetch next bias tile now (covered by exp/PV/next-QK)
        if (kt + 1 < NSEQ / 64) {
            for (int ni = 0; ni < 4; ni++)
                nb[ni] = *(const ushort4*)(bp + (kt+1)*64 + ni*16 + l4*4);
        }
        if (!__all(mj <= mrun + 8.f)) {
            float mnew = fmaxf(mrun, mj);
            float scl = fast_exp2(mrun - mnew);
            lrun *= scl;
            for (int di = 0; di < 4; di++) o[di] *= scl;
            mrun = mnew;
        }
        float rs = 0.f;
        for (int i = 0; i < 16; i++) {
            p[i] = fast_exp2(p[i] - mrun);
            rs += p[i];
        }
        rs += __shfl_xor(rs, 16);
        rs += __shfl_xor(rs, 32);
        lrun += rs;

        // P -> LDS (wave-private), layout [qrow][kseq]
        for (int ni = 0; ni < 4; ni++) {
            ushort4 pk;
            pk.x = f2bf(p[ni*4+0]); pk.y = f2bf(p[ni*4+1]);
            pk.z = f2bf(p[ni*4+2]); pk.w = f2bf(p[ni*4+3]);
            *(ushort4*)&Pls[w][l15][ni*16 + l4*4] = pk;
        }

        // O^T += Vt x P
        __builtin_amdgcn_s_setprio(1);
        for (int ks2 = 0; ks2 < 2; ks2++) {
            short8 pb = *(const short8*)&Pls[w][l15][ks2*32 + l4*8];
            for (int di = 0; di < 4; di++) {
                short8 av = *(const short8*)&Vtls[di*16 + l15][ks2*32 + l4*8];
                o[di] = __builtin_amdgcn_mfma_f32_16x16x32_bf16(av, pb, o[di], 0, 0, 0);
            }
        }
        __builtin_amdgcn_s_setprio(0);

        for (int ni = 0; ni < 4; ni++) cb[ni] = nb[ni];
    }

    float inv = 1.0f / lrun;
    for (int di = 0; di < 4; di++) {
        ushort4 ov;
        ov.x = f2bf(o[di][0] * inv);
        ov.y = f2bf(o[di][1] * inv);
        ov.z = f2bf(o[di][2] * inv);
        ov.w = f2bf(o[di][3] * inv);
        *(ushort4*)(attno + ((size_t)(b*NSEQ + qrow)) * INNER + h*DHEAD + di*16 + l4*4) = ov;
    }
}

extern "C" void kernel_launch(void* const* d_in, const int* in_sizes, int n_in,
                              void* d_out, int out_size, void* d_ws, size_t ws_size,
                              hipStream_t stream) {
    (void)in_sizes; (void)n_in; (void)out_size; (void)ws_size;
    const float* x      = (const float*)d_in[0];
    const float* bias   = (const float*)d_in[1];
    const float* w_qkv  = (const float*)d_in[2];
    const float* w_out  = (const float*)d_in[3];
    const float* b_out  = (const float*)d_in[4];
    const float* gamma  = (const float*)d_in[5];
    const float* beta   = (const float*)d_in[6];
    float* out = (float*)d_out;

    ushort_t* xn    = (ushort_t*)d_ws;
    ushort_t* wqkvT = xn + (size_t)MROWS * DIM;
    ushort_t* woutT = wqkvT + (size_t)1536 * 512;
    ushort_t* qb    = woutT + (size_t)512 * 512;
    ushort_t* kb    = qb + (size_t)MROWS * INNER;
    ushort_t* vt    = kb + (size_t)MROWS * INNER;
    ushort_t* attn  = vt + (size_t)MROWS * INNER;
    ushort_t* biasb = attn + (size_t)MROWS * INNER;

    hipLaunchKernelGGL(prep_kernel, dim3(10496), dim3(256), 0, stream,
                       x, gamma, beta, xn, w_qkv, wqkvT, w_out, woutT, bias, biasb);
    hipLaunchKernelGGL((gemm_kernel<0, 128>), dim3(1536 / 128, MROWS / 128), dim3(256), 0, stream,
                       xn, wqkvT, qb, kb, vt, nullptr, nullptr);
    hipLaunchKernelGGL(attn_kernel, dim3(NSEQ / 64, HEADS, BATCH), dim3(256), 0, stream,
                       qb, kb, vt, biasb, attn);
    hipLaunchKernelGGL((gemm_kernel<1, 64>), dim3(DIM / 64, MROWS / 128), dim3(256), 0, stream,
                       attn, woutT, nullptr, nullptr, nullptr, out, b_out);
}

// Round 8
// 189.521 us; speedup vs baseline: 1.3207x; 1.3207x over previous
//
#include <hip/hip_runtime.h>
#include <hip/hip_bf16.h>

#define DIM 512
#define HEADS 8
#define DHEAD 64
#define INNER 512
#define NSEQ 1024
#define BATCH 8
#define MROWS (BATCH*NSEQ)
#define QK_SCALE 0.125f
#define LOG2E 1.44269504f

typedef __attribute__((ext_vector_type(4))) float f32x4;
typedef __attribute__((ext_vector_type(8))) short short8;
typedef unsigned short ushort_t;

__device__ inline ushort_t f2bf(float f) {
    __hip_bfloat16 h = __float2bfloat16(f);
    return *reinterpret_cast<ushort_t*>(&h);
}
__device__ inline float bf2f(ushort_t u) {
    union { unsigned int i; float f; } c; c.i = ((unsigned int)u) << 16; return c.f;
}
__device__ inline float fast_exp2(float x) {
    float r; asm("v_exp_f32 %0, %1" : "=v"(r) : "v"(x)); return r;
}

// async global->LDS, 16B per lane; LDS dest is wave-uniform base + lane*16.
#define GLD16(gsrc, ldst) __builtin_amdgcn_global_load_lds( \
    (const __attribute__((address_space(1))) void*)(gsrc), \
    (__attribute__((address_space(3))) void*)(ldst), 16, 0, 0)

// ---------------- fused prep: LN + weight transposes + bias cvt(*LOG2E) ----------------
__device__ inline void tc_tile(const float* __restrict__ w, ushort_t* __restrict__ wt,
        int ncols, int n0, int k0, int t, ushort_t (*T)[72]) {
    int kr = t >> 2;
    int nc = (t & 3) * 16;
    const float4* src = (const float4*)(w + (size_t)(k0 + kr) * ncols + n0 + nc);
    float4 f0 = src[0], f1 = src[1], f2 = src[2], f3 = src[3];
    ushort_t tmp[16];
    tmp[0]=f2bf(f0.x); tmp[1]=f2bf(f0.y); tmp[2]=f2bf(f0.z); tmp[3]=f2bf(f0.w);
    tmp[4]=f2bf(f1.x); tmp[5]=f2bf(f1.y); tmp[6]=f2bf(f1.z); tmp[7]=f2bf(f1.w);
    tmp[8]=f2bf(f2.x); tmp[9]=f2bf(f2.y); tmp[10]=f2bf(f2.z); tmp[11]=f2bf(f2.w);
    tmp[12]=f2bf(f3.x); tmp[13]=f2bf(f3.y); tmp[14]=f2bf(f3.z); tmp[15]=f2bf(f3.w);
    *(uint4*)&T[kr][nc]     = *(uint4*)&tmp[0];
    *(uint4*)&T[kr][nc + 8] = *(uint4*)&tmp[8];
    __syncthreads();
    int nr = t >> 2;
    int kc = (t & 3) * 16;
    ushort_t o[16];
    for (int j = 0; j < 16; j++) o[j] = T[kc + j][nr];
    ushort_t* dst = wt + (size_t)(n0 + nr) * 512 + k0 + kc;
    *(uint4*)(dst)     = *(uint4*)&o[0];
    *(uint4*)(dst + 8) = *(uint4*)&o[8];
}

__global__ __launch_bounds__(256) void prep_kernel(
        const float* __restrict__ x, const float* __restrict__ gamma,
        const float* __restrict__ beta, ushort_t* __restrict__ xn,
        const float* __restrict__ w_qkv, ushort_t* __restrict__ wqkvT,
        const float* __restrict__ w_out, ushort_t* __restrict__ woutT,
        const float* __restrict__ bias, ushort_t* __restrict__ biasb) {
    __shared__ ushort_t T[64][72];
    int bid = blockIdx.x;
    int t = threadIdx.x;
    if (bid < 2048) {
        int row = bid * 4 + (t >> 6);
        int lane = t & 63;
        const float4* xr = (const float4*)(x + (size_t)row * DIM);
        float4 a0 = xr[lane];
        float4 a1 = xr[lane + 64];
        float s  = a0.x + a0.y + a0.z + a0.w + a1.x + a1.y + a1.z + a1.w;
        float ss = a0.x*a0.x + a0.y*a0.y + a0.z*a0.z + a0.w*a0.w
                 + a1.x*a1.x + a1.y*a1.y + a1.z*a1.z + a1.w*a1.w;
        for (int off = 1; off < 64; off <<= 1) {
            s  += __shfl_xor(s, off);
            ss += __shfl_xor(ss, off);
        }
        float mean = s * (1.0f / DIM);
        float var  = ss * (1.0f / DIM) - mean * mean;
        float inv  = rsqrtf(var + 1e-5f);
        const float4* g4 = (const float4*)gamma;
        const float4* b4 = (const float4*)beta;
        float4 g0 = g4[lane], g1 = g4[lane + 64];
        float4 be0 = b4[lane], be1 = b4[lane + 64];
        ushort4 o0, o1;
        o0.x = f2bf((a0.x - mean) * inv * g0.x + be0.x);
        o0.y = f2bf((a0.y - mean) * inv * g0.y + be0.y);
        o0.z = f2bf((a0.z - mean) * inv * g0.z + be0.z);
        o0.w = f2bf((a0.w - mean) * inv * g0.w + be0.w);
        o1.x = f2bf((a1.x - mean) * inv * g1.x + be1.x);
        o1.y = f2bf((a1.y - mean) * inv * g1.y + be1.y);
        o1.z = f2bf((a1.z - mean) * inv * g1.z + be1.z);
        o1.w = f2bf((a1.w - mean) * inv * g1.w + be1.w);
        ushort4* outr = (ushort4*)(xn + (size_t)row * DIM);
        outr[lane] = o0;
        outr[lane + 64] = o1;
    } else if (bid < 2240) {
        int rel = bid - 2048;
        tc_tile(w_qkv, wqkvT, 1536, (rel % 24) * 64, (rel / 24) * 64, t, T);
    } else if (bid < 2304) {
        int rel = bid - 2240;
        tc_tile(w_out, woutT, 512, (rel % 8) * 64, (rel / 8) * 64, t, T);
    } else {
        int rel = bid - 2304;
        int i = rel * 256 + t;
        float4 v = ((const float4*)bias)[i];
        ushort4 o;
        o.x = f2bf(v.x * LOG2E); o.y = f2bf(v.y * LOG2E);
        o.z = f2bf(v.z * LOG2E); o.w = f2bf(v.w * LOG2E);
        ((ushort4*)biasb)[i] = o;
    }
}

// ------------- V transpose: vb[b,h,seq,d] -> vt[b,h,d,seq] -------------
__global__ __launch_bounds__(256) void v_transpose(const ushort_t* __restrict__ vb,
        ushort_t* __restrict__ vt) {
    __shared__ ushort_t T[64][72];
    int bh = blockIdx.y;
    int s0 = blockIdx.x * 64;
    int t = threadIdx.x;
    int row = t >> 2, c = (t & 3) * 16;
    const ushort_t* src = vb + ((size_t)bh * NSEQ + s0 + row) * DHEAD + c;
    *(uint4*)&T[row][c]     = *(const uint4*)(src);
    *(uint4*)&T[row][c + 8] = *(const uint4*)(src + 8);
    __syncthreads();
    int d = t >> 2;
    int sq = (t & 3) * 16;
    ushort_t tmp[16];
    for (int j = 0; j < 16; j++) tmp[j] = T[sq + j][d];
    *(uint4*)(vt + ((size_t)bh * DHEAD + d) * NSEQ + s0 + sq)     = *(uint4*)&tmp[0];
    *(uint4*)(vt + ((size_t)bh * DHEAD + d) * NSEQ + s0 + sq + 8) = *(uint4*)&tmp[8];
}

// ---------------- GEMM, m97 structure: 128xBN tile, BK=32, global_load_lds(16B) ----------------
// linear LDS (no pad), 2 barriers/K-step, MFMA overlaps next-tile async loads.
// Swapped MFMA -> lane owns (row=l15, 4 consecutive cols l4*4+j) => vectorized stores.
template<int EPI, int BN>
__global__ __launch_bounds__(256) void gemm_kernel(
        const ushort_t* __restrict__ A, const ushort_t* __restrict__ Bt,
        ushort_t* __restrict__ qb, ushort_t* __restrict__ kb, ushort_t* __restrict__ vb,
        float* __restrict__ outp, const float* __restrict__ bvec) {
    constexpr int BNF = BN / 32;          // n-frags per wave (2 n-waves)
    __shared__ ushort_t Als[128][32];
    __shared__ ushort_t Bls[BN][32];
    int t = threadIdx.x, lane = t & 63, w = t >> 6;
    int bm = blockIdx.y, bn = blockIdx.x;
    int wm = w >> 1, wn = w & 1;
    int l15 = lane & 15, l4 = lane >> 4;
    int lr = lane >> 2, lc = (lane & 3) * 8;   // staging: 16 rows x 32 cols per 1KB chunk

    const ushort_t* gA = A  + (size_t)(bm * 128) * DIM;
    const ushort_t* gB = Bt + (size_t)(bn * BN) * DIM;

    f32x4 acc[4][BNF] = {};

    // prologue: stage tile 0
    {
        GLD16(gA + (size_t)(w*32      + lr) * DIM + lc, &Als[w*32][0]);
        GLD16(gA + (size_t)(w*32 + 16 + lr) * DIM + lc, &Als[w*32 + 16][0]);
        if constexpr (BN == 128) {
            GLD16(gB + (size_t)(w*32      + lr) * DIM + lc, &Bls[w*32][0]);
            GLD16(gB + (size_t)(w*32 + 16 + lr) * DIM + lc, &Bls[w*32 + 16][0]);
        } else {
            GLD16(gB + (size_t)(w*16 + lr) * DIM + lc, &Bls[w*16][0]);
        }
    }

    for (int kt = 0; kt < DIM / 32; ++kt) {
        __syncthreads();   // vmcnt(0) drain -> tile kt resident in LDS
        short8 af[4], bfr[BNF];
        for (int mi = 0; mi < 4; mi++)   af[mi]  = *(const short8*)&Als[wm*64 + mi*16 + l15][l4*8];
        for (int ni = 0; ni < BNF; ni++) bfr[ni] = *(const short8*)&Bls[wn*(BN/2) + ni*16 + l15][l4*8];
        __syncthreads();   // all waves done reading LDS
        if (kt + 1 < DIM / 32) {
            int ko = (kt + 1) * 32;
            GLD16(gA + (size_t)(w*32      + lr) * DIM + ko + lc, &Als[w*32][0]);
            GLD16(gA + (size_t)(w*32 + 16 + lr) * DIM + ko + lc, &Als[w*32 + 16][0]);
            if constexpr (BN == 128) {
                GLD16(gB + (size_t)(w*32      + lr) * DIM + ko + lc, &Bls[w*32][0]);
                GLD16(gB + (size_t)(w*32 + 16 + lr) * DIM + ko + lc, &Bls[w*32 + 16][0]);
            } else {
                GLD16(gB + (size_t)(w*16 + lr) * DIM + ko + lc, &Bls[w*16][0]);
            }
        }
        for (int mi = 0; mi < 4; mi++)
            for (int ni = 0; ni < BNF; ni++)
                acc[mi][ni] = __builtin_amdgcn_mfma_f32_16x16x32_bf16(bfr[ni], af[mi], acc[mi][ni], 0, 0, 0);
    }

    for (int mi = 0; mi < 4; mi++) {
        int r = bm*128 + wm*64 + mi*16 + l15;
        for (int ni = 0; ni < BNF; ni++) {
            int c = bn*BN + wn*(BN/2) + ni*16 + l4*4;
            f32x4 v = acc[mi][ni];
            if (EPI == 0) {
                int part = c >> 9, cw = c & 511;
                int h = cw >> 6, d = cw & 63;
                int b = r >> 10, i = r & 1023;
                size_t off = (((size_t)(b*HEADS + h)) * NSEQ + i) * DHEAD + d;
                ushort4 o;
                if (part == 0) {
                    o.x = f2bf(v[0] * (QK_SCALE*LOG2E)); o.y = f2bf(v[1] * (QK_SCALE*LOG2E));
                    o.z = f2bf(v[2] * (QK_SCALE*LOG2E)); o.w = f2bf(v[3] * (QK_SCALE*LOG2E));
                    *(ushort4*)(qb + off) = o;
                } else if (part == 1) {
                    o.x = f2bf(v[0]); o.y = f2bf(v[1]); o.z = f2bf(v[2]); o.w = f2bf(v[3]);
                    *(ushort4*)(kb + off) = o;
                } else {
                    o.x = f2bf(v[0]); o.y = f2bf(v[1]); o.z = f2bf(v[2]); o.w = f2bf(v[3]);
                    *(ushort4*)(vb + off) = o;
                }
            } else {
                float4 bv = *(const float4*)(bvec + c);
                float4 o2;
                o2.x = v[0] + bv.x; o2.y = v[1] + bv.y;
                o2.z = v[2] + bv.z; o2.w = v[3] + bv.w;
                *(float4*)(outp + (size_t)r * DIM + c) = o2;
            }
        }
    }
}

// ---------------- flash attention, swapped-operand (S^T), exp2 domain ----------------
__global__ __launch_bounds__(256) void attn_kernel(
        const ushort_t* __restrict__ q, const ushort_t* __restrict__ k,
        const ushort_t* __restrict__ vt, const ushort_t* __restrict__ biasb,
        ushort_t* __restrict__ attno) {
    __shared__ ushort_t Kls[64][72];
    __shared__ ushort_t Vtls[64][72];
    __shared__ ushort_t Pls[4][16][72];
    int t = threadIdx.x, lane = t & 63, w = t >> 6;
    int l15 = lane & 15, l4 = lane >> 4;
    int b = blockIdx.z, h = blockIdx.y, q0 = blockIdx.x * 64;
    size_t bh = (size_t)(b * HEADS + h);
    const ushort_t* qp = q  + (bh * NSEQ + q0 + w*16) * DHEAD;
    const ushort_t* kp = k  + bh * NSEQ * DHEAD;
    const ushort_t* vp = vt + bh * DHEAD * NSEQ;
    int qrow = q0 + w*16 + l15;
    const ushort_t* bp = biasb + ((size_t)h * NSEQ + qrow) * NSEQ;

    short8 bq[2];
    bq[0] = *(const short8*)(qp + l15*DHEAD + l4*8);
    bq[1] = *(const short8*)(qp + l15*DHEAD + l4*8 + 32);

    f32x4 o[4] = {};
    float mrun = -INFINITY, lrun = 0.f;

    int srow = t >> 2, sc = (t & 3) * 16;

    uint4 kreg0, kreg1, vreg0, vreg1;
    ushort4 cb[4], nb[4];
    {
        const ushort_t* ks0 = kp + (size_t)srow * DHEAD + sc;
        const ushort_t* vs0 = vp + (size_t)srow * NSEQ + sc;
        kreg0 = *(const uint4*)(ks0);
        kreg1 = *(const uint4*)(ks0 + 8);
        vreg0 = *(const uint4*)(vs0);
        vreg1 = *(const uint4*)(vs0 + 8);
        for (int ni = 0; ni < 4; ni++)
            cb[ni] = *(const ushort4*)(bp + ni*16 + l4*4);
    }

    for (int kt = 0; kt < NSEQ / 64; ++kt) {
        __syncthreads();
        *(uint4*)&Kls[srow][sc]      = kreg0;
        *(uint4*)&Kls[srow][sc + 8]  = kreg1;
        *(uint4*)&Vtls[srow][sc]     = vreg0;
        *(uint4*)&Vtls[srow][sc + 8] = vreg1;
        __syncthreads();

        if (kt + 1 < NSEQ / 64) {
            const ushort_t* ksn = kp + (size_t)((kt+1)*64 + srow) * DHEAD + sc;
            const ushort_t* vsn = vp + (size_t)srow * NSEQ + (kt+1)*64 + sc;
            kreg0 = *(const uint4*)(ksn);
            kreg1 = *(const uint4*)(ksn + 8);
            vreg0 = *(const uint4*)(vsn);
            vreg1 = *(const uint4*)(vsn + 8);
        }

        f32x4 s[4];
        __builtin_amdgcn_s_setprio(1);
        for (int ni = 0; ni < 4; ni++) {
            f32x4 z = {};
            short8 ak0 = *(const short8*)&Kls[ni*16 + l15][l4*8];
            short8 ak1 = *(const short8*)&Kls[ni*16 + l15][l4*8 + 32];
            z = __builtin_amdgcn_mfma_f32_16x16x32_bf16(ak0, bq[0], z, 0, 0, 0);
            z = __builtin_amdgcn_mfma_f32_16x16x32_bf16(ak1, bq[1], z, 0, 0, 0);
            s[ni] = z;
        }
        __builtin_amdgcn_s_setprio(0);

        float p[16];
        float mj = -INFINITY;
        for (int ni = 0; ni < 4; ni++) {
            ushort4 b4 = cb[ni];
            float v0 = s[ni][0] + bf2f(b4.x);
            float v1 = s[ni][1] + bf2f(b4.y);
            float v2 = s[ni][2] + bf2f(b4.z);
            float v3 = s[ni][3] + bf2f(b4.w);
            p[ni*4+0] = v0; p[ni*4+1] = v1; p[ni*4+2] = v2; p[ni*4+3] = v3;
            mj = fmaxf(mj, fmaxf(fmaxf(v0, v1), fmaxf(v2, v3)));
        }
        mj = fmaxf(mj, __shfl_xor(mj, 16));
        mj = fmaxf(mj, __shfl_xor(mj, 32));
        if (kt + 1 < NSEQ / 64) {
            for (int ni = 0; ni < 4; ni++)
                nb[ni] = *(const ushort4*)(bp + (kt+1)*64 + ni*16 + l4*4);
        }
        if (!__all(mj <= mrun + 8.f)) {
            float mnew = fmaxf(mrun, mj);
            float scl = fast_exp2(mrun - mnew);
            lrun *= scl;
            for (int di = 0; di < 4; di++) o[di] *= scl;
            mrun = mnew;
        }
        float rs = 0.f;
        for (int i = 0; i < 16; i++) {
            p[i] = fast_exp2(p[i] - mrun);
            rs += p[i];
        }
        rs += __shfl_xor(rs, 16);
        rs += __shfl_xor(rs, 32);
        lrun += rs;

        for (int ni = 0; ni < 4; ni++) {
            ushort4 pk;
            pk.x = f2bf(p[ni*4+0]); pk.y = f2bf(p[ni*4+1]);
            pk.z = f2bf(p[ni*4+2]); pk.w = f2bf(p[ni*4+3]);
            *(ushort4*)&Pls[w][l15][ni*16 + l4*4] = pk;
        }

        __builtin_amdgcn_s_setprio(1);
        for (int ks2 = 0; ks2 < 2; ks2++) {
            short8 pb = *(const short8*)&Pls[w][l15][ks2*32 + l4*8];
            for (int di = 0; di < 4; di++) {
                short8 av = *(const short8*)&Vtls[di*16 + l15][ks2*32 + l4*8];
                o[di] = __builtin_amdgcn_mfma_f32_16x16x32_bf16(av, pb, o[di], 0, 0, 0);
            }
        }
        __builtin_amdgcn_s_setprio(0);

        for (int ni = 0; ni < 4; ni++) cb[ni] = nb[ni];
    }

    float inv = 1.0f / lrun;
    for (int di = 0; di < 4; di++) {
        ushort4 ov;
        ov.x = f2bf(o[di][0] * inv);
        ov.y = f2bf(o[di][1] * inv);
        ov.z = f2bf(o[di][2] * inv);
        ov.w = f2bf(o[di][3] * inv);
        *(ushort4*)(attno + ((size_t)(b*NSEQ + qrow)) * INNER + h*DHEAD + di*16 + l4*4) = ov;
    }
}

extern "C" void kernel_launch(void* const* d_in, const int* in_sizes, int n_in,
                              void* d_out, int out_size, void* d_ws, size_t ws_size,
                              hipStream_t stream) {
    (void)in_sizes; (void)n_in; (void)out_size; (void)ws_size;
    const float* x      = (const float*)d_in[0];
    const float* bias   = (const float*)d_in[1];
    const float* w_qkv  = (const float*)d_in[2];
    const float* w_out  = (const float*)d_in[3];
    const float* b_out  = (const float*)d_in[4];
    const float* gamma  = (const float*)d_in[5];
    const float* beta   = (const float*)d_in[6];
    float* out = (float*)d_out;

    ushort_t* xn    = (ushort_t*)d_ws;
    ushort_t* wqkvT = xn + (size_t)MROWS * DIM;
    ushort_t* woutT = wqkvT + (size_t)1536 * 512;
    ushort_t* qb    = woutT + (size_t)512 * 512;
    ushort_t* kb    = qb + (size_t)MROWS * INNER;
    ushort_t* vb    = kb + (size_t)MROWS * INNER;
    ushort_t* vt    = vb + (size_t)MROWS * INNER;
    ushort_t* attn  = vt + (size_t)MROWS * INNER;
    ushort_t* biasb = attn + (size_t)MROWS * INNER;

    hipLaunchKernelGGL(prep_kernel, dim3(10496), dim3(256), 0, stream,
                       x, gamma, beta, xn, w_qkv, wqkvT, w_out, woutT, bias, biasb);
    hipLaunchKernelGGL((gemm_kernel<0, 128>), dim3(1536 / 128, MROWS / 128), dim3(256), 0, stream,
                       xn, wqkvT, qb, kb, vb, nullptr, nullptr);
    hipLaunchKernelGGL(v_transpose, dim3(NSEQ / 64, BATCH * HEADS), dim3(256), 0, stream, vb, vt);
    hipLaunchKernelGGL(attn_kernel, dim3(NSEQ / 64, HEADS, BATCH), dim3(256), 0, stream,
                       qb, kb, vt, biasb, attn);
    hipLaunchKernelGGL((gemm_kernel<1, 64>), dim3(DIM / 64, MROWS / 128), dim3(256), 0, stream,
                       attn, woutT, nullptr, nullptr, nullptr, out, b_out);
}